// Round 12
// baseline (85.165 us; speedup 1.0000x reference)
//
#include <hip/hip_runtime.h>

#define EPSF 1e-12f

// ---------------------------------------------------------------------------
// Kernel 1: partial G slices (split-K). grid (n/64, n/64, S), block 256,
// 64x64 tile, 4x4/thread, float4 global+LDS. kchunk = d/S.
// ---------------------------------------------------------------------------
__global__ void gemm_tile(const float* __restrict__ F, float* __restrict__ Gout,
                          int n, int d, int kchunk) {
  __shared__ float As[64][36];
  __shared__ float Bs[64][36];
  const int tid = threadIdx.x;
  const int bx = blockIdx.x, by = blockIdx.y, kz = blockIdx.z;
  const int ty = tid >> 4, tx = tid & 15;
  const int lrow = tid >> 2;
  const int lcol = (tid & 3) * 8;
  const float* Ap = F + (size_t)(bx * 64 + lrow) * d + (size_t)kz * kchunk + lcol;
  const float* Bp = F + (size_t)(by * 64 + lrow) * d + (size_t)kz * kchunk + lcol;
  float acc[4][4];
  for (int r = 0; r < 4; r++)
    for (int c = 0; c < 4; c++) acc[r][c] = 0.0f;

  for (int ks = 0; ks < kchunk; ks += 32) {
    float4 a0 = *(const float4*)(Ap + ks);
    float4 a1 = *(const float4*)(Ap + ks + 4);
    float4 b0 = *(const float4*)(Bp + ks);
    float4 b1 = *(const float4*)(Bp + ks + 4);
    __syncthreads();
    *(float4*)&As[lrow][lcol]     = a0;
    *(float4*)&As[lrow][lcol + 4] = a1;
    *(float4*)&Bs[lrow][lcol]     = b0;
    *(float4*)&Bs[lrow][lcol + 4] = b1;
    __syncthreads();
#pragma unroll
    for (int kk = 0; kk < 32; kk += 4) {
      float4 av[4], bv[4];
#pragma unroll
      for (int r = 0; r < 4; r++) av[r] = *(const float4*)&As[ty + 16 * r][kk];
#pragma unroll
      for (int c = 0; c < 4; c++) bv[c] = *(const float4*)&Bs[tx + 16 * c][kk];
#pragma unroll
      for (int r = 0; r < 4; r++) {
        float4 A = av[r];
#pragma unroll
        for (int c = 0; c < 4; c++) {
          float4 B = bv[c];
          acc[r][c] += A.x * B.x + A.y * B.y + A.z * B.z + A.w * B.w;
        }
      }
    }
  }
  float* Gs = Gout + (size_t)kz * n * n;
#pragma unroll
  for (int r = 0; r < 4; r++)
#pragma unroll
    for (int c = 0; c < 4; c++)
      Gs[(size_t)(bx * 64 + ty + 16 * r) * n + (by * 64 + tx + 16 * c)] =
          acc[r][c];
}

__global__ void reduce_slices(const float* __restrict__ Gp,
                              float* __restrict__ G, int nn, int nslices) {
  int e = (blockIdx.x * 256 + threadIdx.x) * 4;
  if (e < nn) {
    float4 s = *(const float4*)(Gp + e);
    for (int k = 1; k < nslices; k++) {
      float4 t = *(const float4*)(Gp + (size_t)k * nn + e);
      s.x += t.x; s.y += t.y; s.z += t.z; s.w += t.w;
    }
    *(float4*)(G + e) = s;
  }
}

// ---------------------------------------------------------------------------
// Class-dedup loss kernel, LDS-resident. grid (64 classes, 2 row-parts).
// The 128x128 cross-half block M is loaded ONCE coalesced into LDS; stats,
// t_pos, W = exp(M - Ri/2 - Cl/2) (in place) and the SYRK all run from LDS.
// t[i,j] = e^{(Rj-Ri)/2} (W W^T)_ij (exact identity); excluded rows/cols = 0.
// ---------------------------------------------------------------------------
__global__ void TransitionLoss_30666066494151_kernel(
    const float* __restrict__ G, const int* __restrict__ targets,
    float* __restrict__ lsp, float* __restrict__ lan,
    float* __restrict__ cnts, int n) {
  __shared__ float M[128][132];    // 67.6 KB; raw block, then W in place
  __shared__ int tg[256];
  __shared__ int maskA[128], maskB[128];   // 1 = negative (included)
  __shared__ float Ri[128], Cl[128];
  __shared__ float SP[16][17], SQ[16][17];
  __shared__ float red[256];
  __shared__ int Plist[16], Qlist[16];
  __shared__ int ctrP, ctrQ;

  const int tid = threadIdx.x;
  const int cls = blockIdx.x;       // 0..63: (id, half)
  const int part = blockIdx.y;      // 0..1: output row half
  const int nhalf = n >> 1;         // 128
  const int myid = cls & 31;
  const int hA = cls >> 5;
  const int rowA0 = hA * nhalf;
  const int colB0 = nhalf - rowA0;

  tg[tid] = targets[tid];
  if (tid == 0) { ctrP = 0; ctrQ = 0; }
  __syncthreads();

  if (tid < 128) maskA[tid] = (tg[rowA0 + tid] != myid) ? 1 : 0;
  else           maskB[tid - 128] = (tg[colB0 + tid - 128] != myid) ? 1 : 0;

  if (tg[tid] == myid) {
    int inAhalf = (((tid >= nhalf) ? 1 : 0) == hA) ? 1 : 0;
    if (inAhalf) { int k = atomicAdd(&ctrP, 1); if (k < 16) Plist[k] = tid; }
    else         { int k = atomicAdd(&ctrQ, 1); if (k < 16) Qlist[k] = tid; }
  }

  // Coalesced load of the 128x128 cross block: 16 float4 per thread.
  {
    for (int k = 0; k < 16; k++) {
      int e4 = tid + 256 * k;           // 0..4095
      int i = e4 >> 5;                  // row 0..127
      int l4 = (e4 & 31) << 2;          // col 0,4,..,124
      float4 g4 = *(const float4*)(G + (size_t)(rowA0 + i) * n + colB0 + l4);
      *(float4*)&M[i][l4] = g4;
    }
  }
  __syncthreads();

  // LSE stats from LDS. tid<128: Ri[i] over cols (diagonal walk, <=2-way
  // bank); tid>=128: Cl[l] over rows (contiguous lanes, conflict-free).
  if (tid < 128) {
    int i = tid;
    float mx = -1e30f;
    for (int jj = 0; jj < 128; jj++) {
      int l = (jj + i) & 127;
      if (maskB[l]) mx = fmaxf(mx, M[i][l]);
    }
    float s = 0.0f;
    for (int jj = 0; jj < 128; jj++) {
      int l = (jj + i) & 127;
      if (maskB[l]) s += __expf(M[i][l] - mx);
    }
    Ri[i] = maskA[i] ? (mx + __logf(s)) : 0.0f;
  } else {
    int l = tid - 128;
    float mx = -1e30f;
    for (int j = 0; j < 128; j++)
      if (maskA[j]) mx = fmaxf(mx, M[j][l]);
    float s = 0.0f;
    for (int j = 0; j < 128; j++)
      if (maskA[j]) s += __expf(M[j][l] - mx);
    Cl[l] = maskB[l] ? (mx + __logf(s)) : 0.0f;
  }
  __syncthreads();
  const int nP = min(ctrP, 16), nQ = min(ctrQ, 16);

  // t_pos softmaxes straight from LDS M (P rows / Q cols are in this block).
  if (part == 0) {
    if (tid < nP) {
      int ip = Plist[tid] - rowA0;
      float mx = -1e30f;
      for (int q = 0; q < nQ; q++) mx = fmaxf(mx, M[ip][Qlist[q] - colB0]);
      float s = 0.0f;
      for (int q = 0; q < nQ; q++) s += __expf(M[ip][Qlist[q] - colB0] - mx);
      for (int q = 0; q < nQ; q++)
        SP[tid][q] = __expf(M[ip][Qlist[q] - colB0] - mx) / s;
    }
    if (tid >= 64 && tid < 64 + nQ) {
      int q = tid - 64;
      int jq = Qlist[q] - colB0;
      float mx = -1e30f;
      for (int p = 0; p < nP; p++) mx = fmaxf(mx, M[Plist[p] - rowA0][jq]);
      float s = 0.0f;
      for (int p = 0; p < nP; p++) s += __expf(M[Plist[p] - rowA0][jq] - mx);
      for (int p = 0; p < nP; p++)
        SQ[q][p] = __expf(M[Plist[p] - rowA0][jq] - mx) / s;
    }
  }
  __syncthreads();

  // W overwrite in place (contiguous lanes, conflict-free).
  for (int e = tid; e < 128 * 128; e += 256) {
    int i = e >> 7, l = e & 127;
    float v = 0.0f;
    if (maskA[i] && maskB[l])
      v = __expf(M[i][l] - 0.5f * Ri[i] - 0.5f * Cl[l]);  // exponent <= 0
    M[i][l] = v;
  }
  __syncthreads();

  // SYRK over own 64 output rows x 128 cols, K=128 from LDS. 4x8 per thread.
  const int i0 = part * 64;
  const int ty = tid >> 4, tx = tid & 15;
  float acc[4][8];
  for (int r = 0; r < 4; r++)
    for (int c = 0; c < 8; c++) acc[r][c] = 0.0f;

#pragma unroll 4
  for (int kk = 0; kk < 128; kk += 4) {
    float4 av[4], bv[8];
#pragma unroll
    for (int r = 0; r < 4; r++)
      av[r] = *(const float4*)&M[i0 + ty + 16 * r][kk];   // broadcast (free)
#pragma unroll
    for (int c = 0; c < 8; c++)
      bv[c] = *(const float4*)&M[tx + 16 * c][kk];        // <=2-way
#pragma unroll
    for (int r = 0; r < 4; r++) {
      float4 A = av[r];
#pragma unroll
      for (int c = 0; c < 8; c++) {
        float4 B = bv[c];
        acc[r][c] += A.x * B.x + A.y * B.y + A.z * B.z + A.w * B.w;
      }
    }
  }

  // hinge epilogue (excluded rows/cols have acc==0 -> contribute 0)
  float lsum = 0.0f;
  for (int r = 0; r < 4; r++) {
    int i = i0 + ty + 16 * r;
    float ri = Ri[i];
    for (int c = 0; c < 8; c++) {
      int j = tx + 16 * c;
      float t = __expf(0.5f * (Ri[j] - ri)) * acc[r][c];
      lsum += fmaxf(sqrtf(fmaxf(t, EPSF)) - 0.2f, 0.0f);
    }
  }
  red[tid] = lsum;
  __syncthreads();
  for (int s2 = 128; s2 > 0; s2 >>= 1) {
    if (tid < s2) red[tid] += red[tid + s2];
    __syncthreads();
  }
  if (tid == 0) lsp[cls * 2 + part] = red[0];

  if (part == 0) {
    __syncthreads();
    red[tid] = (tid < 128) ? (float)maskA[tid] : 0.0f;   // nA count
    __syncthreads();
    for (int s2 = 128; s2 > 0; s2 >>= 1) {
      if (tid < s2) red[tid] += red[tid + s2];
      __syncthreads();
    }
    if (tid == 0) { cnts[cls * 2 + 0] = red[0]; cnts[cls * 2 + 1] = (float)nP; }

    float lv = 0.0f;
    if (tid < nP * nP) {
      int i = tid / nP, j = tid - i * nP;
      float t = 0.0f;
      for (int l = 0; l < nQ; l++) t += SP[i][l] * SQ[l][j];
      lv = fmaxf(0.5f - sqrtf(fmaxf(t, EPSF)), 0.0f);
    }
    __syncthreads();
    red[tid] = lv;
    __syncthreads();
    for (int s2 = 128; s2 > 0; s2 >>= 1) {
      if (tid < s2) red[tid] += red[tid + s2];
      __syncthreads();
    }
    if (tid == 0) lan[cls] = red[0];
  }
}

// ---------------------------------------------------------------------------
// Accuracy: one wave per anchor. grid 64 x 256 thr (4 waves), coalesced.
// ---------------------------------------------------------------------------
__global__ void accuracy_kernel(const float* __restrict__ G,
                                const int* __restrict__ targets,
                                float* __restrict__ flags, int n) {
  __shared__ float diag[256];
  __shared__ int tg[256];
  const int tid = threadIdx.x;
  const int lane = tid & 63;
  const int w = tid >> 6;
  const int a = blockIdx.x * 4 + w;
  tg[tid] = targets[tid];
  diag[tid] = G[(size_t)tid * (n + 1)];
  __syncthreads();
  const int myid = tg[a];
  const float sqa = diag[a];
  float4 g4 = *(const float4*)(G + (size_t)a * n + lane * 4);
  float gv[4] = {g4.x, g4.y, g4.z, g4.w};
  float dap = -1e30f, dan = 1e30f;
#pragma unroll
  for (int q = 0; q < 4; q++) {
    int j = lane * 4 + q;
    float dist = sqrtf(fmaxf(sqa + diag[j] - 2.0f * gv[q], EPSF));
    if (tg[j] == myid) dap = fmaxf(dap, dist);
    else               dan = fminf(dan, dist);
  }
#pragma unroll
  for (int off = 32; off; off >>= 1) {
    dap = fmaxf(dap, __shfl_xor(dap, off));
    dan = fminf(dan, __shfl_xor(dan, off));
  }
  if (lane == 0) flags[a] = (dan >= dap) ? 1.0f : 0.0f;
}

// ---------------------------------------------------------------------------
// Final: combine 64 classes (weight = nP anchors each) + 256 flags.
// ---------------------------------------------------------------------------
__global__ void final_reduce(const float* __restrict__ lsp,
                             const float* __restrict__ lan,
                             const float* __restrict__ cnts,
                             const float* __restrict__ flags,
                             float* __restrict__ out, int n) {
  __shared__ float rl[256], rf[256];
  const int tid = threadIdx.x;
  float lv = 0.0f;
  if (tid < 64) {
    float nA = cnts[tid * 2 + 0];
    float nP = cnts[tid * 2 + 1];
    if (nP > 0.5f && nA > 0.5f) {
      float lc = (lsp[tid * 2] + lsp[tid * 2 + 1]) / (nA * nA) +
                 lan[tid] / (nP * nP);
      lv = nP * lc;
    }
  }
  rl[tid] = lv;
  rf[tid] = flags[tid];
  __syncthreads();
  for (int s2 = 128; s2 > 0; s2 >>= 1) {
    if (tid < s2) { rl[tid] += rl[tid + s2]; rf[tid] += rf[tid + s2]; }
    __syncthreads();
  }
  if (tid == 0) {
    out[0] = rl[0] / (float)n;
    out[1] = rf[0];
  }
}

extern "C" void kernel_launch(void* const* d_in, const int* in_sizes, int n_in,
                              void* d_out, int out_size, void* d_ws,
                              size_t ws_size, hipStream_t stream) {
  const float* feature = (const float*)d_in[0];
  const int* targets = (const int*)d_in[1];
  const int n = in_sizes[1];            // 256
  const int d = in_sizes[0] / n;        // 2048
  const int nn = n * n;

  int S = 1;
  if (ws_size >= ((size_t)16 * nn + nn + 1024) * sizeof(float)) S = 16;
  else if (ws_size >= ((size_t)4 * nn + nn + 1024) * sizeof(float)) S = 4;

  float* ws = (float*)d_ws;
  float* Gp = ws;
  float* G = (S > 1) ? (ws + (size_t)S * nn) : ws;
  float* lsp = G + nn;        // 128
  float* lan = lsp + 128;     // 64
  float* cnts = lan + 64;     // 128
  float* flags = cnts + 128;  // 256
  float* out = (float*)d_out;

  dim3 gg(n / 64, n / 64, S);
  gemm_tile<<<gg, 256, 0, stream>>>(feature, Gp, n, d, d / S);
  if (S > 1)
    reduce_slices<<<(nn + 1023) / 1024, 256, 0, stream>>>(Gp, G, nn, S);

  dim3 gc(64, 2);
  TransitionLoss_30666066494151_kernel<<<gc, 256, 0, stream>>>(
      G, targets, lsp, lan, cnts, n);

  accuracy_kernel<<<n / 4, 256, 0, stream>>>(G, targets, flags, n);

  final_reduce<<<1, 256, 0, stream>>>(lsp, lan, cnts, flags, out, n);
}

// Round 13
// 66.607 us; speedup vs baseline: 1.2786x; 1.2786x over previous
//
#include <hip/hip_runtime.h>

#define EPSF 1e-12f

// ---------------------------------------------------------------------------
// Kernel 1: partial G slices (split-K). grid (n/64, n/64, S), block 256.
// ---------------------------------------------------------------------------
__global__ void gemm_tile(const float* __restrict__ F, float* __restrict__ Gout,
                          int n, int d, int kchunk) {
  __shared__ float As[64][36];
  __shared__ float Bs[64][36];
  const int tid = threadIdx.x;
  const int bx = blockIdx.x, by = blockIdx.y, kz = blockIdx.z;
  const int ty = tid >> 4, tx = tid & 15;
  const int lrow = tid >> 2;
  const int lcol = (tid & 3) * 8;
  const float* Ap = F + (size_t)(bx * 64 + lrow) * d + (size_t)kz * kchunk + lcol;
  const float* Bp = F + (size_t)(by * 64 + lrow) * d + (size_t)kz * kchunk + lcol;
  float acc[4][4];
  for (int r = 0; r < 4; r++)
    for (int c = 0; c < 4; c++) acc[r][c] = 0.0f;

  for (int ks = 0; ks < kchunk; ks += 32) {
    float4 a0 = *(const float4*)(Ap + ks);
    float4 a1 = *(const float4*)(Ap + ks + 4);
    float4 b0 = *(const float4*)(Bp + ks);
    float4 b1 = *(const float4*)(Bp + ks + 4);
    __syncthreads();
    *(float4*)&As[lrow][lcol]     = a0;
    *(float4*)&As[lrow][lcol + 4] = a1;
    *(float4*)&Bs[lrow][lcol]     = b0;
    *(float4*)&Bs[lrow][lcol + 4] = b1;
    __syncthreads();
#pragma unroll
    for (int kk = 0; kk < 32; kk += 4) {
      float4 av[4], bv[4];
#pragma unroll
      for (int r = 0; r < 4; r++) av[r] = *(const float4*)&As[ty + 16 * r][kk];
#pragma unroll
      for (int c = 0; c < 4; c++) bv[c] = *(const float4*)&Bs[tx + 16 * c][kk];
#pragma unroll
      for (int r = 0; r < 4; r++) {
        float4 A = av[r];
#pragma unroll
        for (int c = 0; c < 4; c++) {
          float4 B = bv[c];
          acc[r][c] += A.x * B.x + A.y * B.y + A.z * B.z + A.w * B.w;
        }
      }
    }
  }
  float* Gs = Gout + (size_t)kz * n * n;
#pragma unroll
  for (int r = 0; r < 4; r++)
#pragma unroll
    for (int c = 0; c < 4; c++)
      Gs[(size_t)(bx * 64 + ty + 16 * r) * n + (by * 64 + tx + 16 * c)] =
          acc[r][c];
}

__global__ void reduce_slices(const float* __restrict__ Gp,
                              float* __restrict__ G, int nn, int nslices) {
  int e = (blockIdx.x * 256 + threadIdx.x) * 4;
  if (e < nn) {
    float4 s = *(const float4*)(Gp + e);
    for (int k = 1; k < nslices; k++) {
      float4 t = *(const float4*)(Gp + (size_t)k * nn + e);
      s.x += t.x; s.y += t.y; s.z += t.z; s.w += t.w;
    }
    *(float4*)(G + e) = s;
  }
}

// ---------------------------------------------------------------------------
// Row-LSE table: LSE[r][id] = logsumexp over opposite-half cols c with
// tg[c]!=id of G[r][c]. One wave per row; global-max scaling + per-id bins +
// stable exclusive sum via left/right positive prefix scans (no cancellation).
// grid 64 x 256 thr (4 waves -> 4 rows/block).
// ---------------------------------------------------------------------------
__global__ void row_lse_kernel(const float* __restrict__ G,
                               const int* __restrict__ targets,
                               float* __restrict__ LSEtab, int n) {
  __shared__ float bins[4][33];
  __shared__ int tg[256];
  const int tid = threadIdx.x;
  const int lane = tid & 63;
  const int w = tid >> 6;
  tg[tid] = targets[tid];
  if (tid < 128) bins[tid >> 5][tid & 31] = 0.0f;
  __syncthreads();

  const int r = blockIdx.x * 4 + w;
  const int nhalf = n >> 1;
  const int opp0 = (r < nhalf) ? nhalf : 0;
  float2 v = *(const float2*)(G + (size_t)r * n + opp0 + lane * 2);
  const int id0 = tg[opp0 + lane * 2];
  const int id1 = tg[opp0 + lane * 2 + 1];

  float mx = fmaxf(v.x, v.y);
#pragma unroll
  for (int off = 32; off; off >>= 1) mx = fmaxf(mx, __shfl_xor(mx, off));

  atomicAdd(&bins[w][id0], __expf(v.x - mx));
  atomicAdd(&bins[w][id1], __expf(v.y - mx));
  __syncthreads();

  if (lane < 32) {
    float b = bins[w][lane];
    // strict-left sum (positive prefix scan of left-shifted bins)
    float lv = __shfl_up(b, 1, 32);
    if (lane == 0) lv = 0.0f;
#pragma unroll
    for (int off = 1; off < 32; off <<= 1) {
      float t = __shfl_up(lv, off, 32);
      if (lane >= off) lv += t;
    }
    // strict-right sum
    float rv = __shfl_down(b, 1, 32);
    if (lane == 31) rv = 0.0f;
#pragma unroll
    for (int off = 1; off < 32; off <<= 1) {
      float t = __shfl_down(rv, off, 32);
      if (lane + off < 32) rv += t;
    }
    float excl = fmaxf(lv + rv, 1e-37f);
    LSEtab[(size_t)r * 32 + lane] = mx + __logf(excl);
  }
}

// ---------------------------------------------------------------------------
// Class-dedup loss kernel, LDS-resident, stats from LSE table.
// grid (64 classes, 2 row-parts), block 256.
// W[i][l] = exp(M_il - Ri/2 - Cl/2); t = e^{(Rj-Ri)/2} (W W^T)_ij (exact).
// ---------------------------------------------------------------------------
__global__ void TransitionLoss_30666066494151_kernel(
    const float* __restrict__ G, const int* __restrict__ targets,
    const float* __restrict__ LSEtab, float* __restrict__ lsp,
    float* __restrict__ lan, float* __restrict__ cnts, int n) {
  __shared__ float M[128][132];    // 67.6 KB; raw block, then W in place
  __shared__ int tg[256];
  __shared__ int maskA[128], maskB[128];
  __shared__ float Ri[128], Cl[128];
  __shared__ float SP[16][17], SQ[16][17];
  __shared__ float red[256];
  __shared__ int Plist[16], Qlist[16];
  __shared__ int ctrP, ctrQ;

  const int tid = threadIdx.x;
  const int cls = blockIdx.x;
  const int part = blockIdx.y;
  const int nhalf = n >> 1;
  const int myid = cls & 31;
  const int hA = cls >> 5;
  const int rowA0 = hA * nhalf;
  const int colB0 = nhalf - rowA0;

  tg[tid] = targets[tid];
  if (tid == 0) { ctrP = 0; ctrQ = 0; }
  __syncthreads();

  if (tid < 128) {
    maskA[tid] = (tg[rowA0 + tid] != myid) ? 1 : 0;
    Ri[tid] = LSEtab[(size_t)(rowA0 + tid) * 32 + myid];
  } else {
    maskB[tid - 128] = (tg[colB0 + tid - 128] != myid) ? 1 : 0;
    Cl[tid - 128] = LSEtab[(size_t)(colB0 + tid - 128) * 32 + myid];
  }

  if (tg[tid] == myid) {
    int inAhalf = (((tid >= nhalf) ? 1 : 0) == hA) ? 1 : 0;
    if (inAhalf) { int k = atomicAdd(&ctrP, 1); if (k < 16) Plist[k] = tid; }
    else         { int k = atomicAdd(&ctrQ, 1); if (k < 16) Qlist[k] = tid; }
  }

  // Coalesced load of the 128x128 cross block: 16 float4 per thread.
#pragma unroll
  for (int k = 0; k < 16; k++) {
    int e4 = tid + 256 * k;
    int i = e4 >> 5;
    int l4 = (e4 & 31) << 2;
    float4 g4 = *(const float4*)(G + (size_t)(rowA0 + i) * n + colB0 + l4);
    *(float4*)&M[i][l4] = g4;
  }
  __syncthreads();
  const int nP = min(ctrP, 16), nQ = min(ctrQ, 16);

  // t_pos softmaxes from raw LDS M (P rows / Q cols are in this block).
  if (part == 0) {
    if (tid < nP) {
      int ip = Plist[tid] - rowA0;
      float mx = -1e30f;
      for (int q = 0; q < nQ; q++) mx = fmaxf(mx, M[ip][Qlist[q] - colB0]);
      float s = 0.0f;
      for (int q = 0; q < nQ; q++) s += __expf(M[ip][Qlist[q] - colB0] - mx);
      for (int q = 0; q < nQ; q++)
        SP[tid][q] = __expf(M[ip][Qlist[q] - colB0] - mx) / s;
    }
    if (tid >= 64 && tid < 64 + nQ) {
      int q = tid - 64;
      int jq = Qlist[q] - colB0;
      float mx = -1e30f;
      for (int p = 0; p < nP; p++) mx = fmaxf(mx, M[Plist[p] - rowA0][jq]);
      float s = 0.0f;
      for (int p = 0; p < nP; p++) s += __expf(M[Plist[p] - rowA0][jq] - mx);
      for (int p = 0; p < nP; p++)
        SQ[q][p] = __expf(M[Plist[p] - rowA0][jq] - mx) / s;
    }
  }
  __syncthreads();

  // W overwrite in place (contiguous lanes, conflict-free).
  for (int e = tid; e < 128 * 128; e += 256) {
    int i = e >> 7, l = e & 127;
    float v = 0.0f;
    if (maskA[i] && maskB[l])
      v = __expf(M[i][l] - 0.5f * Ri[i] - 0.5f * Cl[l]);
    M[i][l] = v;
  }
  __syncthreads();

  // SYRK over own 64 output rows x 128 cols, K=128 from LDS. 4x8 per thread.
  const int i0 = part * 64;
  const int ty = tid >> 4, tx = tid & 15;
  float acc[4][8];
  for (int r = 0; r < 4; r++)
    for (int c = 0; c < 8; c++) acc[r][c] = 0.0f;

#pragma unroll 4
  for (int kk = 0; kk < 128; kk += 4) {
    float4 av[4], bv[8];
#pragma unroll
    for (int r = 0; r < 4; r++)
      av[r] = *(const float4*)&M[i0 + ty + 16 * r][kk];
#pragma unroll
    for (int c = 0; c < 8; c++)
      bv[c] = *(const float4*)&M[tx + 16 * c][kk];
#pragma unroll
    for (int r = 0; r < 4; r++) {
      float4 A = av[r];
#pragma unroll
      for (int c = 0; c < 8; c++) {
        float4 B = bv[c];
        acc[r][c] += A.x * B.x + A.y * B.y + A.z * B.z + A.w * B.w;
      }
    }
  }

  float lsum = 0.0f;
  for (int r = 0; r < 4; r++) {
    int i = i0 + ty + 16 * r;
    float ri = Ri[i];
    for (int c = 0; c < 8; c++) {
      int j = tx + 16 * c;
      float t = __expf(0.5f * (Ri[j] - ri)) * acc[r][c];
      lsum += fmaxf(sqrtf(fmaxf(t, EPSF)) - 0.2f, 0.0f);
    }
  }
  red[tid] = lsum;
  __syncthreads();
  for (int s2 = 128; s2 > 0; s2 >>= 1) {
    if (tid < s2) red[tid] += red[tid + s2];
    __syncthreads();
  }
  if (tid == 0) lsp[cls * 2 + part] = red[0];

  if (part == 0) {
    __syncthreads();
    red[tid] = (tid < 128) ? (float)maskA[tid] : 0.0f;
    __syncthreads();
    for (int s2 = 128; s2 > 0; s2 >>= 1) {
      if (tid < s2) red[tid] += red[tid + s2];
      __syncthreads();
    }
    if (tid == 0) { cnts[cls * 2 + 0] = red[0]; cnts[cls * 2 + 1] = (float)nP; }

    float lv = 0.0f;
    if (tid < nP * nP) {
      int i = tid / nP, j = tid - i * nP;
      float t = 0.0f;
      for (int l = 0; l < nQ; l++) t += SP[i][l] * SQ[l][j];
      lv = fmaxf(0.5f - sqrtf(fmaxf(t, EPSF)), 0.0f);
    }
    __syncthreads();
    red[tid] = lv;
    __syncthreads();
    for (int s2 = 128; s2 > 0; s2 >>= 1) {
      if (tid < s2) red[tid] += red[tid + s2];
      __syncthreads();
    }
    if (tid == 0) lan[cls] = red[0];
  }
}

// ---------------------------------------------------------------------------
// Accuracy: one wave per anchor. grid 64 x 256 thr.
// ---------------------------------------------------------------------------
__global__ void accuracy_kernel(const float* __restrict__ G,
                                const int* __restrict__ targets,
                                float* __restrict__ flags, int n) {
  __shared__ float diag[256];
  __shared__ int tg[256];
  const int tid = threadIdx.x;
  const int lane = tid & 63;
  const int w = tid >> 6;
  const int a = blockIdx.x * 4 + w;
  tg[tid] = targets[tid];
  diag[tid] = G[(size_t)tid * (n + 1)];
  __syncthreads();
  const int myid = tg[a];
  const float sqa = diag[a];
  float4 g4 = *(const float4*)(G + (size_t)a * n + lane * 4);
  float gv[4] = {g4.x, g4.y, g4.z, g4.w};
  float dap = -1e30f, dan = 1e30f;
#pragma unroll
  for (int q = 0; q < 4; q++) {
    int j = lane * 4 + q;
    float dist = sqrtf(fmaxf(sqa + diag[j] - 2.0f * gv[q], EPSF));
    if (tg[j] == myid) dap = fmaxf(dap, dist);
    else               dan = fminf(dan, dist);
  }
#pragma unroll
  for (int off = 32; off; off >>= 1) {
    dap = fmaxf(dap, __shfl_xor(dap, off));
    dan = fminf(dan, __shfl_xor(dan, off));
  }
  if (lane == 0) flags[a] = (dan >= dap) ? 1.0f : 0.0f;
}

__global__ void final_reduce(const float* __restrict__ lsp,
                             const float* __restrict__ lan,
                             const float* __restrict__ cnts,
                             const float* __restrict__ flags,
                             float* __restrict__ out, int n) {
  __shared__ float rl[256], rf[256];
  const int tid = threadIdx.x;
  float lv = 0.0f;
  if (tid < 64) {
    float nA = cnts[tid * 2 + 0];
    float nP = cnts[tid * 2 + 1];
    if (nP > 0.5f && nA > 0.5f) {
      float lc = (lsp[tid * 2] + lsp[tid * 2 + 1]) / (nA * nA) +
                 lan[tid] / (nP * nP);
      lv = nP * lc;
    }
  }
  rl[tid] = lv;
  rf[tid] = flags[tid];
  __syncthreads();
  for (int s2 = 128; s2 > 0; s2 >>= 1) {
    if (tid < s2) { rl[tid] += rl[tid + s2]; rf[tid] += rf[tid + s2]; }
    __syncthreads();
  }
  if (tid == 0) {
    out[0] = rl[0] / (float)n;
    out[1] = rf[0];
  }
}

extern "C" void kernel_launch(void* const* d_in, const int* in_sizes, int n_in,
                              void* d_out, int out_size, void* d_ws,
                              size_t ws_size, hipStream_t stream) {
  const float* feature = (const float*)d_in[0];
  const int* targets = (const int*)d_in[1];
  const int n = in_sizes[1];            // 256
  const int d = in_sizes[0] / n;        // 2048
  const int nn = n * n;
  const size_t small = 128 + 64 + 128 + 256 + (size_t)n * 32;  // scalars+LSE

  int S = 1;
  if (ws_size >= (small + nn + (size_t)16 * nn) * sizeof(float)) S = 16;
  else if (ws_size >= (small + nn + (size_t)4 * nn) * sizeof(float)) S = 4;

  float* ws = (float*)d_ws;
  float* lsp = ws;                 // 128
  float* lan = lsp + 128;          // 64
  float* cnts = lan + 64;          // 128
  float* flags = cnts + 128;       // 256
  float* LSEtab = flags + 256;     // n*32
  float* G = LSEtab + (size_t)n * 32;   // nn
  float* Gp = (S > 1) ? (G + nn) : G;   // S*nn slices (or alias G when S==1)
  float* out = (float*)d_out;

  dim3 gg(n / 64, n / 64, S);
  gemm_tile<<<gg, 256, 0, stream>>>(feature, Gp, n, d, d / S);
  if (S > 1)
    reduce_slices<<<(nn + 1023) / 1024, 256, 0, stream>>>(Gp, G, nn, S);

  row_lse_kernel<<<n / 4, 256, 0, stream>>>(G, targets, LSEtab, n);

  dim3 gc(64, 2);
  TransitionLoss_30666066494151_kernel<<<gc, 256, 0, stream>>>(
      G, targets, LSEtab, lsp, lan, cnts, n);

  accuracy_kernel<<<n / 4, 256, 0, stream>>>(G, targets, flags, n);

  final_reduce<<<1, 256, 0, stream>>>(lsp, lan, cnts, flags, out, n);
}

// Round 14
// 58.252 us; speedup vs baseline: 1.4620x; 1.1434x over previous
//
#include <hip/hip_runtime.h>

#define EPSF 1e-12f

__device__ __forceinline__ unsigned short f2bf(float f) {
  unsigned int u = __float_as_uint(f);
  unsigned int r = u + 0x7fffu + ((u >> 16) & 1u);  // RNE
  return (unsigned short)(r >> 16);
}
#define BFLO(u) __uint_as_float((u) << 16)
#define BFHI(u) __uint_as_float((u) & 0xffff0000u)

// ---------------------------------------------------------------------------
// Kernel 1: partial G slices (split-K). grid (n/64, n/64, S), block 256.
// ---------------------------------------------------------------------------
__global__ void gemm_tile(const float* __restrict__ F, float* __restrict__ Gout,
                          int n, int d, int kchunk) {
  __shared__ float As[64][36];
  __shared__ float Bs[64][36];
  const int tid = threadIdx.x;
  const int bx = blockIdx.x, by = blockIdx.y, kz = blockIdx.z;
  const int ty = tid >> 4, tx = tid & 15;
  const int lrow = tid >> 2;
  const int lcol = (tid & 3) * 8;
  const float* Ap = F + (size_t)(bx * 64 + lrow) * d + (size_t)kz * kchunk + lcol;
  const float* Bp = F + (size_t)(by * 64 + lrow) * d + (size_t)kz * kchunk + lcol;
  float acc[4][4];
  for (int r = 0; r < 4; r++)
    for (int c = 0; c < 4; c++) acc[r][c] = 0.0f;

  for (int ks = 0; ks < kchunk; ks += 32) {
    float4 a0 = *(const float4*)(Ap + ks);
    float4 a1 = *(const float4*)(Ap + ks + 4);
    float4 b0 = *(const float4*)(Bp + ks);
    float4 b1 = *(const float4*)(Bp + ks + 4);
    __syncthreads();
    *(float4*)&As[lrow][lcol]     = a0;
    *(float4*)&As[lrow][lcol + 4] = a1;
    *(float4*)&Bs[lrow][lcol]     = b0;
    *(float4*)&Bs[lrow][lcol + 4] = b1;
    __syncthreads();
#pragma unroll
    for (int kk = 0; kk < 32; kk += 4) {
      float4 av[4], bv[4];
#pragma unroll
      for (int r = 0; r < 4; r++) av[r] = *(const float4*)&As[ty + 16 * r][kk];
#pragma unroll
      for (int c = 0; c < 4; c++) bv[c] = *(const float4*)&Bs[tx + 16 * c][kk];
#pragma unroll
      for (int r = 0; r < 4; r++) {
        float4 A = av[r];
#pragma unroll
        for (int c = 0; c < 4; c++) {
          float4 B = bv[c];
          acc[r][c] += A.x * B.x + A.y * B.y + A.z * B.z + A.w * B.w;
        }
      }
    }
  }
  float* Gs = Gout + (size_t)kz * n * n;
#pragma unroll
  for (int r = 0; r < 4; r++)
#pragma unroll
    for (int c = 0; c < 4; c++)
      Gs[(size_t)(bx * 64 + ty + 16 * r) * n + (by * 64 + tx + 16 * c)] =
          acc[r][c];
}

__global__ void reduce_slices(const float* __restrict__ Gp,
                              float* __restrict__ G, int nn, int nslices) {
  int e = (blockIdx.x * 256 + threadIdx.x) * 4;
  if (e < nn) {
    float4 s = *(const float4*)(Gp + e);
    for (int k = 1; k < nslices; k++) {
      float4 t = *(const float4*)(Gp + (size_t)k * nn + e);
      s.x += t.x; s.y += t.y; s.z += t.z; s.w += t.w;
    }
    *(float4*)(G + e) = s;
  }
}

// ---------------------------------------------------------------------------
// Fused stats kernel: per row r (one wave each) computes
//  (a) accuracy flag (dan >= dap over full row),
//  (b) LSE[r][id] over opposite-half cols c with tg[c]!=id, via global-max
//      scaling + per-id bins + strict left/right positive prefix sums.
// grid 64 x 256 thr (4 waves -> 4 rows/block).
// ---------------------------------------------------------------------------
__global__ void stats_kernel(const float* __restrict__ G,
                             const int* __restrict__ targets,
                             float* __restrict__ LSEtab,
                             float* __restrict__ flags, int n) {
  __shared__ float bins[4][33];
  __shared__ int tg[256];
  __shared__ float diag[256];
  const int tid = threadIdx.x;
  const int lane = tid & 63;
  const int w = tid >> 6;
  tg[tid] = targets[tid];
  diag[tid] = G[(size_t)tid * (n + 1)];
  if (tid < 128) bins[tid >> 5][tid & 31] = 0.0f;
  __syncthreads();

  const int r = blockIdx.x * 4 + w;
  const int nhalf = n >> 1;
  const int opp0 = (r < nhalf) ? nhalf : 0;
  const int myid = tg[r];
  const float sqr = diag[r];

  float4 v = *(const float4*)(G + (size_t)r * n + lane * 4);
  float gv[4] = {v.x, v.y, v.z, v.w};

  // accuracy over the full row
  float dap = -1e30f, dan = 1e30f;
#pragma unroll
  for (int q = 0; q < 4; q++) {
    int j = lane * 4 + q;
    float dist = sqrtf(fmaxf(sqr + diag[j] - 2.0f * gv[q], EPSF));
    if (tg[j] == myid) dap = fmaxf(dap, dist);
    else               dan = fminf(dan, dist);
  }
#pragma unroll
  for (int off = 32; off; off >>= 1) {
    dap = fmaxf(dap, __shfl_xor(dap, off));
    dan = fminf(dan, __shfl_xor(dan, off));
  }
  if (lane == 0) flags[r] = (dan >= dap) ? 1.0f : 0.0f;

  // LSE bins over the opposite half (cols opp0..opp0+127 = lanes' j in range)
  float mx = -1e30f;
#pragma unroll
  for (int q = 0; q < 4; q++) {
    int j = lane * 4 + q;
    if (j >= opp0 && j < opp0 + nhalf) mx = fmaxf(mx, gv[q]);
  }
#pragma unroll
  for (int off = 32; off; off >>= 1) mx = fmaxf(mx, __shfl_xor(mx, off));

#pragma unroll
  for (int q = 0; q < 4; q++) {
    int j = lane * 4 + q;
    if (j >= opp0 && j < opp0 + nhalf)
      atomicAdd(&bins[w][tg[j]], __expf(gv[q] - mx));
  }
  __syncthreads();

  if (lane < 32) {
    float b = bins[w][lane];
    float lv = __shfl_up(b, 1, 32);
    if (lane == 0) lv = 0.0f;
#pragma unroll
    for (int off = 1; off < 32; off <<= 1) {
      float t = __shfl_up(lv, off, 32);
      if (lane >= off) lv += t;
    }
    float rv = __shfl_down(b, 1, 32);
    if (lane == 31) rv = 0.0f;
#pragma unroll
    for (int off = 1; off < 32; off <<= 1) {
      float t = __shfl_down(rv, off, 32);
      if (lane + off < 32) rv += t;
    }
    float excl = fmaxf(lv + rv, 1e-37f);
    LSEtab[(size_t)r * 32 + lane] = mx + __logf(excl);
  }
}

// ---------------------------------------------------------------------------
// Class-dedup loss kernel. grid (64 classes, 8 row-parts), block 256.
// W computed on the fly during the G load (Ri/Cl from LSE table), stored
// bf16 in LDS (34.8 KB -> 2+ blocks/CU). Part p computes output rows
// [p*16, p*16+16) x 128 cols. t = e^{(Rj-Ri)/2} (W W^T)_ij (exact identity).
// ---------------------------------------------------------------------------
__global__ void TransitionLoss_30666066494151_kernel(
    const float* __restrict__ G, const int* __restrict__ targets,
    const float* __restrict__ LSEtab, float* __restrict__ lsp,
    float* __restrict__ lan, float* __restrict__ cnts, int n) {
  __shared__ unsigned short W[128][136];   // 34816 B bf16; row 272 B
  __shared__ int tg[256];
  __shared__ int maskA[128], maskB[128];
  __shared__ float Ri[128], Cl[128];
  __shared__ float SP[16][17], SQ[16][17];
  __shared__ float red[256];
  __shared__ int Plist[16], Qlist[16];
  __shared__ int ctrP, ctrQ;

  const int tid = threadIdx.x;
  const int cls = blockIdx.x;       // (id, half)
  const int part = blockIdx.y;      // 0..7 -> rows [part*16, part*16+16)
  const int nhalf = n >> 1;
  const int myid = cls & 31;
  const int hA = cls >> 5;
  const int rowA0 = hA * nhalf;
  const int colB0 = nhalf - rowA0;

  tg[tid] = targets[tid];
  if (tid == 0) { ctrP = 0; ctrQ = 0; }
  __syncthreads();

  if (tid < 128) {
    maskA[tid] = (tg[rowA0 + tid] != myid) ? 1 : 0;
    Ri[tid] = LSEtab[(size_t)(rowA0 + tid) * 32 + myid];
  } else {
    maskB[tid - 128] = (tg[colB0 + tid - 128] != myid) ? 1 : 0;
    Cl[tid - 128] = LSEtab[(size_t)(colB0 + tid - 128) * 32 + myid];
  }
  if (tg[tid] == myid) {
    int inAhalf = (((tid >= nhalf) ? 1 : 0) == hA) ? 1 : 0;
    if (inAhalf) { int k = atomicAdd(&ctrP, 1); if (k < 16) Plist[k] = tid; }
    else         { int k = atomicAdd(&ctrQ, 1); if (k < 16) Qlist[k] = tid; }
  }
  __syncthreads();

  // Fused load + W fill (bf16). 4096 float4 over 256 threads.
#pragma unroll
  for (int k = 0; k < 16; k++) {
    int e4 = tid + 256 * k;
    int i = e4 >> 5;
    int l4 = (e4 & 31) << 2;
    float4 g4 = *(const float4*)(G + (size_t)(rowA0 + i) * n + colB0 + l4);
    float rih = 0.5f * Ri[i];
    int ma = maskA[i];
    float w0 = (ma && maskB[l4 + 0]) ? __expf(g4.x - rih - 0.5f * Cl[l4 + 0]) : 0.0f;
    float w1 = (ma && maskB[l4 + 1]) ? __expf(g4.y - rih - 0.5f * Cl[l4 + 1]) : 0.0f;
    float w2 = (ma && maskB[l4 + 2]) ? __expf(g4.z - rih - 0.5f * Cl[l4 + 2]) : 0.0f;
    float w3 = (ma && maskB[l4 + 3]) ? __expf(g4.w - rih - 0.5f * Cl[l4 + 3]) : 0.0f;
    uint2 packed;
    packed.x = (unsigned)f2bf(w0) | ((unsigned)f2bf(w1) << 16);
    packed.y = (unsigned)f2bf(w2) | ((unsigned)f2bf(w3) << 16);
    *(uint2*)&W[i][l4] = packed;
  }
  __syncthreads();
  const int nP = min(ctrP, 16), nQ = min(ctrQ, 16);

  // SYRK: rows [part*16 .. +16) x 128 cols, K=128 bf16 from LDS.
  const int i0 = part * 16;
  const int ty = tid >> 4, tx = tid & 15;
  const float riA = Ri[i0 + ty];
  float acc[8];
#pragma unroll
  for (int c = 0; c < 8; c++) acc[c] = 0.0f;

#pragma unroll 2
  for (int kk = 0; kk < 128; kk += 8) {
    uint4 ar = *(const uint4*)&W[i0 + ty][kk];
    float a0 = BFLO(ar.x), a1 = BFHI(ar.x), a2 = BFLO(ar.y), a3 = BFHI(ar.y);
    float a4 = BFLO(ar.z), a5 = BFHI(ar.z), a6 = BFLO(ar.w), a7 = BFHI(ar.w);
#pragma unroll
    for (int c = 0; c < 8; c++) {
      uint4 br = *(const uint4*)&W[tx + 16 * c][kk];
      acc[c] += a0 * BFLO(br.x) + a1 * BFHI(br.x) +
                a2 * BFLO(br.y) + a3 * BFHI(br.y) +
                a4 * BFLO(br.z) + a5 * BFHI(br.z) +
                a6 * BFLO(br.w) + a7 * BFHI(br.w);
    }
  }

  // hinge epilogue
  float lsum = 0.0f;
#pragma unroll
  for (int c = 0; c < 8; c++) {
    int j = tx + 16 * c;
    float t = __expf(0.5f * (Ri[j] - riA)) * acc[c];
    lsum += fmaxf(sqrtf(fmaxf(t, EPSF)) - 0.2f, 0.0f);
  }
  red[tid] = lsum;
  __syncthreads();
  for (int s2 = 128; s2 > 0; s2 >>= 1) {
    if (tid < s2) red[tid] += red[tid + s2];
    __syncthreads();
  }
  if (tid == 0) lsp[cls * 8 + part] = red[0];

  if (part == 0) {
    __syncthreads();
    red[tid] = (tid < 128) ? (float)maskA[tid] : 0.0f;
    __syncthreads();
    for (int s2 = 128; s2 > 0; s2 >>= 1) {
      if (tid < s2) red[tid] += red[tid + s2];
      __syncthreads();
    }
    if (tid == 0) { cnts[cls * 2 + 0] = red[0]; cnts[cls * 2 + 1] = (float)nP; }

    // t_pos from global G (tiny scattered reads, L2-resident)
    if (tid < nP) {
      const float* gr = G + (size_t)Plist[tid] * n;
      float mx = -1e30f;
      for (int q = 0; q < nQ; q++) mx = fmaxf(mx, gr[Qlist[q]]);
      float s = 0.0f;
      for (int q = 0; q < nQ; q++) s += __expf(gr[Qlist[q]] - mx);
      for (int q = 0; q < nQ; q++) SP[tid][q] = __expf(gr[Qlist[q]] - mx) / s;
    }
    if (tid >= 64 && tid < 64 + nQ) {
      int q = tid - 64;
      const float* gr = G + (size_t)Qlist[q] * n;
      float mx = -1e30f;
      for (int p = 0; p < nP; p++) mx = fmaxf(mx, gr[Plist[p]]);
      float s = 0.0f;
      for (int p = 0; p < nP; p++) s += __expf(gr[Plist[p]] - mx);
      for (int p = 0; p < nP; p++) SQ[q][p] = __expf(gr[Plist[p]] - mx) / s;
    }
    __syncthreads();
    float lv = 0.0f;
    if (tid < nP * nP) {
      int i = tid / nP, j = tid - i * nP;
      float t = 0.0f;
      for (int l = 0; l < nQ; l++) t += SP[i][l] * SQ[l][j];
      lv = fmaxf(0.5f - sqrtf(fmaxf(t, EPSF)), 0.0f);
    }
    red[tid] = lv;
    __syncthreads();
    for (int s2 = 128; s2 > 0; s2 >>= 1) {
      if (tid < s2) red[tid] += red[tid + s2];
      __syncthreads();
    }
    if (tid == 0) lan[cls] = red[0];
  }
}

__global__ void final_reduce(const float* __restrict__ lsp,
                             const float* __restrict__ lan,
                             const float* __restrict__ cnts,
                             const float* __restrict__ flags,
                             float* __restrict__ out, int n) {
  __shared__ float rl[256], rf[256];
  const int tid = threadIdx.x;
  float lv = 0.0f;
  if (tid < 64) {
    float nA = cnts[tid * 2 + 0];
    float nP = cnts[tid * 2 + 1];
    if (nP > 0.5f && nA > 0.5f) {
      float s = 0.0f;
      for (int p = 0; p < 8; p++) s += lsp[tid * 8 + p];
      float lc = s / (nA * nA) + lan[tid] / (nP * nP);
      lv = nP * lc;
    }
  }
  rl[tid] = lv;
  rf[tid] = flags[tid];
  __syncthreads();
  for (int s2 = 128; s2 > 0; s2 >>= 1) {
    if (tid < s2) { rl[tid] += rl[tid + s2]; rf[tid] += rf[tid + s2]; }
    __syncthreads();
  }
  if (tid == 0) {
    out[0] = rl[0] / (float)n;
    out[1] = rf[0];
  }
}

extern "C" void kernel_launch(void* const* d_in, const int* in_sizes, int n_in,
                              void* d_out, int out_size, void* d_ws,
                              size_t ws_size, hipStream_t stream) {
  const float* feature = (const float*)d_in[0];
  const int* targets = (const int*)d_in[1];
  const int n = in_sizes[1];            // 256
  const int d = in_sizes[0] / n;        // 2048
  const int nn = n * n;
  const size_t small = 512 + 64 + 128 + 256 + (size_t)n * 32;

  int S = 1;
  if (ws_size >= (small + nn + (size_t)16 * nn) * sizeof(float)) S = 16;
  else if (ws_size >= (small + nn + (size_t)4 * nn) * sizeof(float)) S = 4;

  float* ws = (float*)d_ws;
  float* lsp = ws;                 // 512 (64 cls x 8 parts)
  float* lan = lsp + 512;          // 64
  float* cnts = lan + 64;          // 128
  float* flags = cnts + 128;       // 256
  float* LSEtab = flags + 256;     // n*32
  float* G = LSEtab + (size_t)n * 32;   // nn
  float* Gp = (S > 1) ? (G + nn) : G;
  float* out = (float*)d_out;

  dim3 gg(n / 64, n / 64, S);
  gemm_tile<<<gg, 256, 0, stream>>>(feature, Gp, n, d, d / S);
  if (S > 1)
    reduce_slices<<<(nn + 1023) / 1024, 256, 0, stream>>>(Gp, G, nn, S);

  stats_kernel<<<n / 4, 256, 0, stream>>>(G, targets, LSEtab, flags, n);

  dim3 gc(64, 8);
  TransitionLoss_30666066494151_kernel<<<gc, 256, 0, stream>>>(
      G, targets, LSEtab, lsp, lan, cnts, n);

  final_reduce<<<1, 256, 0, stream>>>(lsp, lan, cnts, flags, out, n);
}

// Round 15
// 56.575 us; speedup vs baseline: 1.5053x; 1.0296x over previous
//
#include <hip/hip_runtime.h>

#define EPSF 1e-12f

__device__ __forceinline__ unsigned short f2bf(float f) {
  unsigned int u = __float_as_uint(f);
  unsigned int r = u + 0x7fffu + ((u >> 16) & 1u);  // RNE
  return (unsigned short)(r >> 16);
}
#define BFLO(u) __uint_as_float((u) << 16)
#define BFHI(u) __uint_as_float((u) & 0xffff0000u)

// ---------------------------------------------------------------------------
// Kernel 1: partial G slices (split-K). grid (n/64, n/64, S), block 256.
// ---------------------------------------------------------------------------
__global__ void gemm_tile(const float* __restrict__ F, float* __restrict__ Gout,
                          int n, int d, int kchunk) {
  __shared__ float As[64][36];
  __shared__ float Bs[64][36];
  const int tid = threadIdx.x;
  const int bx = blockIdx.x, by = blockIdx.y, kz = blockIdx.z;
  const int ty = tid >> 4, tx = tid & 15;
  const int lrow = tid >> 2;
  const int lcol = (tid & 3) * 8;
  const float* Ap = F + (size_t)(bx * 64 + lrow) * d + (size_t)kz * kchunk + lcol;
  const float* Bp = F + (size_t)(by * 64 + lrow) * d + (size_t)kz * kchunk + lcol;
  float acc[4][4];
  for (int r = 0; r < 4; r++)
    for (int c = 0; c < 4; c++) acc[r][c] = 0.0f;

  for (int ks = 0; ks < kchunk; ks += 32) {
    float4 a0 = *(const float4*)(Ap + ks);
    float4 a1 = *(const float4*)(Ap + ks + 4);
    float4 b0 = *(const float4*)(Bp + ks);
    float4 b1 = *(const float4*)(Bp + ks + 4);
    __syncthreads();
    *(float4*)&As[lrow][lcol]     = a0;
    *(float4*)&As[lrow][lcol + 4] = a1;
    *(float4*)&Bs[lrow][lcol]     = b0;
    *(float4*)&Bs[lrow][lcol + 4] = b1;
    __syncthreads();
#pragma unroll
    for (int kk = 0; kk < 32; kk += 4) {
      float4 av[4], bv[4];
#pragma unroll
      for (int r = 0; r < 4; r++) av[r] = *(const float4*)&As[ty + 16 * r][kk];
#pragma unroll
      for (int c = 0; c < 4; c++) bv[c] = *(const float4*)&Bs[tx + 16 * c][kk];
#pragma unroll
      for (int r = 0; r < 4; r++) {
        float4 A = av[r];
#pragma unroll
        for (int c = 0; c < 4; c++) {
          float4 B = bv[c];
          acc[r][c] += A.x * B.x + A.y * B.y + A.z * B.z + A.w * B.w;
        }
      }
    }
  }
  float* Gs = Gout + (size_t)kz * n * n;
#pragma unroll
  for (int r = 0; r < 4; r++)
#pragma unroll
    for (int c = 0; c < 4; c++)
      Gs[(size_t)(bx * 64 + ty + 16 * r) * n + (by * 64 + tx + 16 * c)] =
          acc[r][c];
}

__global__ void reduce_slices(const float* __restrict__ Gp,
                              float* __restrict__ G, int nn, int nslices) {
  int e = (blockIdx.x * 256 + threadIdx.x) * 4;
  if (e < nn) {
    float4 s = *(const float4*)(Gp + e);
    for (int k = 1; k < nslices; k++) {
      float4 t = *(const float4*)(Gp + (size_t)k * nn + e);
      s.x += t.x; s.y += t.y; s.z += t.z; s.w += t.w;
    }
    *(float4*)(G + e) = s;
  }
}

// ---------------------------------------------------------------------------
// Fused stats kernel: accuracy flags + LSE[r][id] table. grid 64 x 256.
// ---------------------------------------------------------------------------
__global__ void stats_kernel(const float* __restrict__ G,
                             const int* __restrict__ targets,
                             float* __restrict__ LSEtab,
                             float* __restrict__ flags, int n) {
  __shared__ float bins[4][33];
  __shared__ int tg[256];
  __shared__ float diag[256];
  const int tid = threadIdx.x;
  const int lane = tid & 63;
  const int w = tid >> 6;
  tg[tid] = targets[tid];
  diag[tid] = G[(size_t)tid * (n + 1)];
  if (tid < 128) bins[tid >> 5][tid & 31] = 0.0f;
  __syncthreads();

  const int r = blockIdx.x * 4 + w;
  const int nhalf = n >> 1;
  const int opp0 = (r < nhalf) ? nhalf : 0;
  const int myid = tg[r];
  const float sqr = diag[r];

  float4 v = *(const float4*)(G + (size_t)r * n + lane * 4);
  float gv[4] = {v.x, v.y, v.z, v.w};

  float dap = -1e30f, dan = 1e30f;
#pragma unroll
  for (int q = 0; q < 4; q++) {
    int j = lane * 4 + q;
    float dist = sqrtf(fmaxf(sqr + diag[j] - 2.0f * gv[q], EPSF));
    if (tg[j] == myid) dap = fmaxf(dap, dist);
    else               dan = fminf(dan, dist);
  }
#pragma unroll
  for (int off = 32; off; off >>= 1) {
    dap = fmaxf(dap, __shfl_xor(dap, off));
    dan = fminf(dan, __shfl_xor(dan, off));
  }
  if (lane == 0) flags[r] = (dan >= dap) ? 1.0f : 0.0f;

  float mx = -1e30f;
#pragma unroll
  for (int q = 0; q < 4; q++) {
    int j = lane * 4 + q;
    if (j >= opp0 && j < opp0 + nhalf) mx = fmaxf(mx, gv[q]);
  }
#pragma unroll
  for (int off = 32; off; off >>= 1) mx = fmaxf(mx, __shfl_xor(mx, off));

#pragma unroll
  for (int q = 0; q < 4; q++) {
    int j = lane * 4 + q;
    if (j >= opp0 && j < opp0 + nhalf)
      atomicAdd(&bins[w][tg[j]], __expf(gv[q] - mx));
  }
  __syncthreads();

  if (lane < 32) {
    float b = bins[w][lane];
    float lv = __shfl_up(b, 1, 32);
    if (lane == 0) lv = 0.0f;
#pragma unroll
    for (int off = 1; off < 32; off <<= 1) {
      float t = __shfl_up(lv, off, 32);
      if (lane >= off) lv += t;
    }
    float rv = __shfl_down(b, 1, 32);
    if (lane == 31) rv = 0.0f;
#pragma unroll
    for (int off = 1; off < 32; off <<= 1) {
      float t = __shfl_down(rv, off, 32);
      if (lane + off < 32) rv += t;
    }
    float excl = fmaxf(lv + rv, 1e-37f);
    LSEtab[(size_t)r * 32 + lane] = mx + __logf(excl);
  }
}

// ---------------------------------------------------------------------------
// Class-dedup loss kernel. grid (64 classes, 8 row-parts), block 256.
// W bf16 in LDS, computed on the fly. Part 0 additionally computes t_pos
// with a PARALLEL 16x16 gather (one latency round, no serial chains).
// ---------------------------------------------------------------------------
__global__ void TransitionLoss_30666066494151_kernel(
    const float* __restrict__ G, const int* __restrict__ targets,
    const float* __restrict__ LSEtab, float* __restrict__ lsp,
    float* __restrict__ lan, float* __restrict__ cnts, int n) {
  __shared__ unsigned short W[128][136];   // 34816 B bf16
  __shared__ int tg[256];
  __shared__ int maskA[128], maskB[128];
  __shared__ float Ri[128], Cl[128];
  __shared__ float SMRAW[16][17];
  __shared__ float SP[16][17], SQ[16][17];
  __shared__ float red[256];
  __shared__ int Plist[16], Qlist[16];
  __shared__ int ctrP, ctrQ;

  const int tid = threadIdx.x;
  const int cls = blockIdx.x;
  const int part = blockIdx.y;      // 0..7 -> rows [part*16, part*16+16)
  const int nhalf = n >> 1;
  const int myid = cls & 31;
  const int hA = cls >> 5;
  const int rowA0 = hA * nhalf;
  const int colB0 = nhalf - rowA0;

  tg[tid] = targets[tid];
  if (tid == 0) { ctrP = 0; ctrQ = 0; }
  __syncthreads();

  if (tid < 128) {
    maskA[tid] = (tg[rowA0 + tid] != myid) ? 1 : 0;
    Ri[tid] = LSEtab[(size_t)(rowA0 + tid) * 32 + myid];
  } else {
    maskB[tid - 128] = (tg[colB0 + tid - 128] != myid) ? 1 : 0;
    Cl[tid - 128] = LSEtab[(size_t)(colB0 + tid - 128) * 32 + myid];
  }
  if (tg[tid] == myid) {
    int inAhalf = (((tid >= nhalf) ? 1 : 0) == hA) ? 1 : 0;
    if (inAhalf) { int k = atomicAdd(&ctrP, 1); if (k < 16) Plist[k] = tid; }
    else         { int k = atomicAdd(&ctrQ, 1); if (k < 16) Qlist[k] = tid; }
  }
  __syncthreads();
  const int nP = min(ctrP, 16), nQ = min(ctrQ, 16);

  // Fused load + W fill (bf16), 4 loads in flight per group.
#pragma unroll
  for (int k4 = 0; k4 < 4; k4++) {
    float4 g[4];
#pragma unroll
    for (int u = 0; u < 4; u++) {
      int e4 = tid + 256 * (k4 * 4 + u);
      int i = e4 >> 5;
      int l4 = (e4 & 31) << 2;
      g[u] = *(const float4*)(G + (size_t)(rowA0 + i) * n + colB0 + l4);
    }
#pragma unroll
    for (int u = 0; u < 4; u++) {
      int e4 = tid + 256 * (k4 * 4 + u);
      int i = e4 >> 5;
      int l4 = (e4 & 31) << 2;
      float rih = 0.5f * Ri[i];
      int ma = maskA[i];
      float w0 = (ma && maskB[l4 + 0]) ? __expf(g[u].x - rih - 0.5f * Cl[l4 + 0]) : 0.0f;
      float w1 = (ma && maskB[l4 + 1]) ? __expf(g[u].y - rih - 0.5f * Cl[l4 + 1]) : 0.0f;
      float w2 = (ma && maskB[l4 + 2]) ? __expf(g[u].z - rih - 0.5f * Cl[l4 + 2]) : 0.0f;
      float w3 = (ma && maskB[l4 + 3]) ? __expf(g[u].w - rih - 0.5f * Cl[l4 + 3]) : 0.0f;
      uint2 packed;
      packed.x = (unsigned)f2bf(w0) | ((unsigned)f2bf(w1) << 16);
      packed.y = (unsigned)f2bf(w2) | ((unsigned)f2bf(w3) << 16);
      *(uint2*)&W[i][l4] = packed;
    }
  }

  // t_pos parallel gather (part 0 only): 256 threads fetch the 16x16 block
  // in ONE latency round; softmaxes then run from LDS.
  if (part == 0) {
    int p = tid >> 4, q = tid & 15;
    float v = 0.0f;
    if (p < nP && q < nQ) v = G[(size_t)Plist[p] * n + Qlist[q]];
    SMRAW[p][q] = v;
  }
  __syncthreads();

  // SYRK: rows [part*16 .. +16) x 128 cols, K=128 bf16 from LDS.
  const int i0 = part * 16;
  const int ty = tid >> 4, tx = tid & 15;
  const float riA = Ri[i0 + ty];
  float acc[8];
#pragma unroll
  for (int c = 0; c < 8; c++) acc[c] = 0.0f;

#pragma unroll 2
  for (int kk = 0; kk < 128; kk += 8) {
    uint4 ar = *(const uint4*)&W[i0 + ty][kk];
    float a0 = BFLO(ar.x), a1 = BFHI(ar.x), a2 = BFLO(ar.y), a3 = BFHI(ar.y);
    float a4 = BFLO(ar.z), a5 = BFHI(ar.z), a6 = BFLO(ar.w), a7 = BFHI(ar.w);
#pragma unroll
    for (int c = 0; c < 8; c++) {
      uint4 br = *(const uint4*)&W[tx + 16 * c][kk];
      acc[c] += a0 * BFLO(br.x) + a1 * BFHI(br.x) +
                a2 * BFLO(br.y) + a3 * BFHI(br.y) +
                a4 * BFLO(br.z) + a5 * BFHI(br.z) +
                a6 * BFLO(br.w) + a7 * BFHI(br.w);
    }
  }

  float lsum = 0.0f;
#pragma unroll
  for (int c = 0; c < 8; c++) {
    int j = tx + 16 * c;
    float t = __expf(0.5f * (Ri[j] - riA)) * acc[c];
    lsum += fmaxf(sqrtf(fmaxf(t, EPSF)) - 0.2f, 0.0f);
  }
  red[tid] = lsum;
  __syncthreads();
  for (int s2 = 128; s2 > 0; s2 >>= 1) {
    if (tid < s2) red[tid] += red[tid + s2];
    __syncthreads();
  }
  if (tid == 0) lsp[cls * 8 + part] = red[0];

  if (part == 0) {
    __syncthreads();
    red[tid] = (tid < 128) ? (float)maskA[tid] : 0.0f;
    __syncthreads();
    for (int s2 = 128; s2 > 0; s2 >>= 1) {
      if (tid < s2) red[tid] += red[tid + s2];
      __syncthreads();
    }
    if (tid == 0) { cnts[cls * 2 + 0] = red[0]; cnts[cls * 2 + 1] = (float)nP; }

    // softmaxes over the LDS-resident 16x16 raw block
    if (tid < nP) {
      float mx = -1e30f;
      for (int q = 0; q < nQ; q++) mx = fmaxf(mx, SMRAW[tid][q]);
      float s = 0.0f;
      for (int q = 0; q < nQ; q++) s += __expf(SMRAW[tid][q] - mx);
      for (int q = 0; q < nQ; q++) SP[tid][q] = __expf(SMRAW[tid][q] - mx) / s;
    }
    if (tid >= 64 && tid < 64 + nQ) {
      int q = tid - 64;
      float mx = -1e30f;
      for (int p = 0; p < nP; p++) mx = fmaxf(mx, SMRAW[p][q]);
      float s = 0.0f;
      for (int p = 0; p < nP; p++) s += __expf(SMRAW[p][q] - mx);
      for (int p = 0; p < nP; p++) SQ[q][p] = __expf(SMRAW[p][q] - mx) / s;
    }
    __syncthreads();
    float lv = 0.0f;
    if (tid < nP * nP) {
      int i = tid / nP, j = tid - i * nP;
      float t = 0.0f;
      for (int l = 0; l < nQ; l++) t += SP[i][l] * SQ[l][j];
      lv = fmaxf(0.5f - sqrtf(fmaxf(t, EPSF)), 0.0f);
    }
    red[tid] = lv;
    __syncthreads();
    for (int s2 = 128; s2 > 0; s2 >>= 1) {
      if (tid < s2) red[tid] += red[tid + s2];
      __syncthreads();
    }
    if (tid == 0) lan[cls] = red[0];
  }
}

__global__ void final_reduce(const float* __restrict__ lsp,
                             const float* __restrict__ lan,
                             const float* __restrict__ cnts,
                             const float* __restrict__ flags,
                             float* __restrict__ out, int n) {
  __shared__ float rl[256], rf[256];
  const int tid = threadIdx.x;
  float lv = 0.0f;
  if (tid < 64) {
    float nA = cnts[tid * 2 + 0];
    float nP = cnts[tid * 2 + 1];
    if (nP > 0.5f && nA > 0.5f) {
      float s = 0.0f;
      for (int p = 0; p < 8; p++) s += lsp[tid * 8 + p];
      float lc = s / (nA * nA) + lan[tid] / (nP * nP);
      lv = nP * lc;
    }
  }
  rl[tid] = lv;
  rf[tid] = flags[tid];
  __syncthreads();
  for (int s2 = 128; s2 > 0; s2 >>= 1) {
    if (tid < s2) { rl[tid] += rl[tid + s2]; rf[tid] += rf[tid + s2]; }
    __syncthreads();
  }
  if (tid == 0) {
    out[0] = rl[0] / (float)n;
    out[1] = rf[0];
  }
}

extern "C" void kernel_launch(void* const* d_in, const int* in_sizes, int n_in,
                              void* d_out, int out_size, void* d_ws,
                              size_t ws_size, hipStream_t stream) {
  const float* feature = (const float*)d_in[0];
  const int* targets = (const int*)d_in[1];
  const int n = in_sizes[1];            // 256
  const int d = in_sizes[0] / n;        // 2048
  const int nn = n * n;
  const size_t small = 512 + 64 + 128 + 256 + (size_t)n * 32;

  int S = 1;
  if (ws_size >= (small + nn + (size_t)16 * nn) * sizeof(float)) S = 16;
  else if (ws_size >= (small + nn + (size_t)4 * nn) * sizeof(float)) S = 4;

  float* ws = (float*)d_ws;
  float* lsp = ws;                 // 512
  float* lan = lsp + 512;          // 64
  float* cnts = lan + 64;          // 128
  float* flags = cnts + 128;       // 256
  float* LSEtab = flags + 256;     // n*32
  float* G = LSEtab + (size_t)n * 32;   // nn
  float* Gp = (S > 1) ? (G + nn) : G;
  float* out = (float*)d_out;

  dim3 gg(n / 64, n / 64, S);
  gemm_tile<<<gg, 256, 0, stream>>>(feature, Gp, n, d, d / S);
  if (S > 1)
    reduce_slices<<<(nn + 1023) / 1024, 256, 0, stream>>>(Gp, G, nn, S);

  stats_kernel<<<n / 4, 256, 0, stream>>>(G, targets, LSEtab, flags, n);

  dim3 gc(64, 8);
  TransitionLoss_30666066494151_kernel<<<gc, 256, 0, stream>>>(
      G, targets, LSEtab, lsp, lan, cnts, n);

  final_reduce<<<1, 256, 0, stream>>>(lsp, lan, cnts, flags, out, n);
}

// Round 16
// 56.148 us; speedup vs baseline: 1.5168x; 1.0076x over previous
//
#include <hip/hip_runtime.h>

#define EPSF 1e-12f

__device__ __forceinline__ unsigned short f2bf(float f) {
  unsigned int u = __float_as_uint(f);
  unsigned int r = u + 0x7fffu + ((u >> 16) & 1u);  // RNE
  return (unsigned short)(r >> 16);
}
#define BFLO(u) __uint_as_float((u) << 16)
#define BFHI(u) __uint_as_float((u) & 0xffff0000u)

// ---------------------------------------------------------------------------
// Kernel 1: partial G slices (split-K). grid (n/64, n/64, S), block 256.
// ---------------------------------------------------------------------------
__global__ void gemm_tile(const float* __restrict__ F, float* __restrict__ Gout,
                          int n, int d, int kchunk) {
  __shared__ float As[64][36];
  __shared__ float Bs[64][36];
  const int tid = threadIdx.x;
  const int bx = blockIdx.x, by = blockIdx.y, kz = blockIdx.z;
  const int ty = tid >> 4, tx = tid & 15;
  const int lrow = tid >> 2;
  const int lcol = (tid & 3) * 8;
  const float* Ap = F + (size_t)(bx * 64 + lrow) * d + (size_t)kz * kchunk + lcol;
  const float* Bp = F + (size_t)(by * 64 + lrow) * d + (size_t)kz * kchunk + lcol;
  float acc[4][4];
  for (int r = 0; r < 4; r++)
    for (int c = 0; c < 4; c++) acc[r][c] = 0.0f;

  for (int ks = 0; ks < kchunk; ks += 32) {
    float4 a0 = *(const float4*)(Ap + ks);
    float4 a1 = *(const float4*)(Ap + ks + 4);
    float4 b0 = *(const float4*)(Bp + ks);
    float4 b1 = *(const float4*)(Bp + ks + 4);
    __syncthreads();
    *(float4*)&As[lrow][lcol]     = a0;
    *(float4*)&As[lrow][lcol + 4] = a1;
    *(float4*)&Bs[lrow][lcol]     = b0;
    *(float4*)&Bs[lrow][lcol + 4] = b1;
    __syncthreads();
#pragma unroll
    for (int kk = 0; kk < 32; kk += 4) {
      float4 av[4], bv[4];
#pragma unroll
      for (int r = 0; r < 4; r++) av[r] = *(const float4*)&As[ty + 16 * r][kk];
#pragma unroll
      for (int c = 0; c < 4; c++) bv[c] = *(const float4*)&Bs[tx + 16 * c][kk];
#pragma unroll
      for (int r = 0; r < 4; r++) {
        float4 A = av[r];
#pragma unroll
        for (int c = 0; c < 4; c++) {
          float4 B = bv[c];
          acc[r][c] += A.x * B.x + A.y * B.y + A.z * B.z + A.w * B.w;
        }
      }
    }
  }
  float* Gs = Gout + (size_t)kz * n * n;
#pragma unroll
  for (int r = 0; r < 4; r++)
#pragma unroll
    for (int c = 0; c < 4; c++)
      Gs[(size_t)(bx * 64 + ty + 16 * r) * n + (by * 64 + tx + 16 * c)] =
          acc[r][c];
}

__global__ void reduce_slices(const float* __restrict__ Gp,
                              float* __restrict__ G, int nn, int nslices) {
  int e = (blockIdx.x * 256 + threadIdx.x) * 4;
  if (e < nn) {
    float4 s = *(const float4*)(Gp + e);
    for (int k = 1; k < nslices; k++) {
      float4 t = *(const float4*)(Gp + (size_t)k * nn + e);
      s.x += t.x; s.y += t.y; s.z += t.z; s.w += t.w;
    }
    *(float4*)(G + e) = s;
  }
}

// ---------------------------------------------------------------------------
// Fused stats kernel: accuracy flags + LSE[r][id] table. grid 64 x 256.
// ---------------------------------------------------------------------------
__global__ void stats_kernel(const float* __restrict__ G,
                             const int* __restrict__ targets,
                             float* __restrict__ LSEtab,
                             float* __restrict__ flags, int n) {
  __shared__ float bins[4][33];
  __shared__ int tg[256];
  __shared__ float diag[256];
  const int tid = threadIdx.x;
  const int lane = tid & 63;
  const int w = tid >> 6;
  tg[tid] = targets[tid];
  diag[tid] = G[(size_t)tid * (n + 1)];
  if (tid < 128) bins[tid >> 5][tid & 31] = 0.0f;
  __syncthreads();

  const int r = blockIdx.x * 4 + w;
  const int nhalf = n >> 1;
  const int opp0 = (r < nhalf) ? nhalf : 0;
  const int myid = tg[r];
  const float sqr = diag[r];

  float4 v = *(const float4*)(G + (size_t)r * n + lane * 4);
  float gv[4] = {v.x, v.y, v.z, v.w};

  float dap = -1e30f, dan = 1e30f;
#pragma unroll
  for (int q = 0; q < 4; q++) {
    int j = lane * 4 + q;
    float dist = sqrtf(fmaxf(sqr + diag[j] - 2.0f * gv[q], EPSF));
    if (tg[j] == myid) dap = fmaxf(dap, dist);
    else               dan = fminf(dan, dist);
  }
#pragma unroll
  for (int off = 32; off; off >>= 1) {
    dap = fmaxf(dap, __shfl_xor(dap, off));
    dan = fminf(dan, __shfl_xor(dan, off));
  }
  if (lane == 0) flags[r] = (dan >= dap) ? 1.0f : 0.0f;

  float mx = -1e30f;
#pragma unroll
  for (int q = 0; q < 4; q++) {
    int j = lane * 4 + q;
    if (j >= opp0 && j < opp0 + nhalf) mx = fmaxf(mx, gv[q]);
  }
#pragma unroll
  for (int off = 32; off; off >>= 1) mx = fmaxf(mx, __shfl_xor(mx, off));

#pragma unroll
  for (int q = 0; q < 4; q++) {
    int j = lane * 4 + q;
    if (j >= opp0 && j < opp0 + nhalf)
      atomicAdd(&bins[w][tg[j]], __expf(gv[q] - mx));
  }
  __syncthreads();

  if (lane < 32) {
    float b = bins[w][lane];
    float lv = __shfl_up(b, 1, 32);
    if (lane == 0) lv = 0.0f;
#pragma unroll
    for (int off = 1; off < 32; off <<= 1) {
      float t = __shfl_up(lv, off, 32);
      if (lane >= off) lv += t;
    }
    float rv = __shfl_down(b, 1, 32);
    if (lane == 31) rv = 0.0f;
#pragma unroll
    for (int off = 1; off < 32; off <<= 1) {
      float t = __shfl_down(rv, off, 32);
      if (lane + off < 32) rv += t;
    }
    float excl = fmaxf(lv + rv, 1e-37f);
    LSEtab[(size_t)r * 32 + lane] = mx + __logf(excl);
  }
}

// ---------------------------------------------------------------------------
// Class-dedup loss kernel. grid (64 classes, 8 row-parts), block 256.
// __launch_bounds__(256,2): allow ~128 VGPRs so the 8 B-column LDS reads
// per k-step live in independent registers (ILP) instead of a serialized
// 4-VGPR reuse chain (the r15 stall: VGPR_Count=40).
// ---------------------------------------------------------------------------
__global__ __launch_bounds__(256, 2) void TransitionLoss_30666066494151_kernel(
    const float* __restrict__ G, const int* __restrict__ targets,
    const float* __restrict__ LSEtab, float* __restrict__ lsp,
    float* __restrict__ lan, float* __restrict__ cnts, int n) {
  __shared__ unsigned short W[128][136];   // 34816 B bf16
  __shared__ int tg[256];
  __shared__ int maskA[128], maskB[128];
  __shared__ float Ri[128], Cl[128];
  __shared__ float SMRAW[16][17];
  __shared__ float SP[16][17], SQ[16][17];
  __shared__ float red[256];
  __shared__ int Plist[16], Qlist[16];
  __shared__ int ctrP, ctrQ;

  const int tid = threadIdx.x;
  const int cls = blockIdx.x;
  const int part = blockIdx.y;      // 0..7 -> rows [part*16, part*16+16)
  const int nhalf = n >> 1;
  const int myid = cls & 31;
  const int hA = cls >> 5;
  const int rowA0 = hA * nhalf;
  const int colB0 = nhalf - rowA0;

  tg[tid] = targets[tid];
  if (tid == 0) { ctrP = 0; ctrQ = 0; }
  __syncthreads();

  if (tid < 128) {
    maskA[tid] = (tg[rowA0 + tid] != myid) ? 1 : 0;
    Ri[tid] = LSEtab[(size_t)(rowA0 + tid) * 32 + myid];
  } else {
    maskB[tid - 128] = (tg[colB0 + tid - 128] != myid) ? 1 : 0;
    Cl[tid - 128] = LSEtab[(size_t)(colB0 + tid - 128) * 32 + myid];
  }
  if (tg[tid] == myid) {
    int inAhalf = (((tid >= nhalf) ? 1 : 0) == hA) ? 1 : 0;
    if (inAhalf) { int k = atomicAdd(&ctrP, 1); if (k < 16) Plist[k] = tid; }
    else         { int k = atomicAdd(&ctrQ, 1); if (k < 16) Qlist[k] = tid; }
  }
  __syncthreads();
  const int nP = min(ctrP, 16), nQ = min(ctrQ, 16);

  // Fused load + W fill (bf16): 16 float4, 8 in flight per group.
#pragma unroll
  for (int k8 = 0; k8 < 2; k8++) {
    float4 g[8];
#pragma unroll
    for (int u = 0; u < 8; u++) {
      int e4 = tid + 256 * (k8 * 8 + u);
      int i = e4 >> 5;
      int l4 = (e4 & 31) << 2;
      g[u] = *(const float4*)(G + (size_t)(rowA0 + i) * n + colB0 + l4);
    }
#pragma unroll
    for (int u = 0; u < 8; u++) {
      int e4 = tid + 256 * (k8 * 8 + u);
      int i = e4 >> 5;
      int l4 = (e4 & 31) << 2;
      float rih = 0.5f * Ri[i];
      int ma = maskA[i];
      float w0 = (ma && maskB[l4 + 0]) ? __expf(g[u].x - rih - 0.5f * Cl[l4 + 0]) : 0.0f;
      float w1 = (ma && maskB[l4 + 1]) ? __expf(g[u].y - rih - 0.5f * Cl[l4 + 1]) : 0.0f;
      float w2 = (ma && maskB[l4 + 2]) ? __expf(g[u].z - rih - 0.5f * Cl[l4 + 2]) : 0.0f;
      float w3 = (ma && maskB[l4 + 3]) ? __expf(g[u].w - rih - 0.5f * Cl[l4 + 3]) : 0.0f;
      uint2 packed;
      packed.x = (unsigned)f2bf(w0) | ((unsigned)f2bf(w1) << 16);
      packed.y = (unsigned)f2bf(w2) | ((unsigned)f2bf(w3) << 16);
      *(uint2*)&W[i][l4] = packed;
    }
  }

  // t_pos parallel gather (part 0 only): one latency round.
  if (part == 0) {
    int p = tid >> 4, q = tid & 15;
    float v = 0.0f;
    if (p < nP && q < nQ) v = G[(size_t)Plist[p] * n + Qlist[q]];
    SMRAW[p][q] = v;
  }
  __syncthreads();

  // SYRK: rows [part*16 .. +16) x 128 cols, K=128 bf16 from LDS.
  // All 8 B-reads issued into independent registers BEFORE any unpack/FMA.
  const int i0 = part * 16;
  const int ty = tid >> 4, tx = tid & 15;
  const float riA = Ri[i0 + ty];
  float acc[8];
#pragma unroll
  for (int c = 0; c < 8; c++) acc[c] = 0.0f;

  for (int kk = 0; kk < 128; kk += 8) {
    uint4 ar = *(const uint4*)&W[i0 + ty][kk];
    uint4 br[8];
#pragma unroll
    for (int c = 0; c < 8; c++) br[c] = *(const uint4*)&W[tx + 16 * c][kk];
    float a0 = BFLO(ar.x), a1 = BFHI(ar.x), a2 = BFLO(ar.y), a3 = BFHI(ar.y);
    float a4 = BFLO(ar.z), a5 = BFHI(ar.z), a6 = BFLO(ar.w), a7 = BFHI(ar.w);
#pragma unroll
    for (int c = 0; c < 8; c++) {
      acc[c] += a0 * BFLO(br[c].x) + a1 * BFHI(br[c].x) +
                a2 * BFLO(br[c].y) + a3 * BFHI(br[c].y) +
                a4 * BFLO(br[c].z) + a5 * BFHI(br[c].z) +
                a6 * BFLO(br[c].w) + a7 * BFHI(br[c].w);
    }
  }

  float lsum = 0.0f;
#pragma unroll
  for (int c = 0; c < 8; c++) {
    int j = tx + 16 * c;
    float t = __expf(0.5f * (Ri[j] - riA)) * acc[c];
    lsum += fmaxf(sqrtf(fmaxf(t, EPSF)) - 0.2f, 0.0f);
  }
  red[tid] = lsum;
  __syncthreads();
  for (int s2 = 128; s2 > 0; s2 >>= 1) {
    if (tid < s2) red[tid] += red[tid + s2];
    __syncthreads();
  }
  if (tid == 0) lsp[cls * 8 + part] = red[0];

  if (part == 0) {
    __syncthreads();
    red[tid] = (tid < 128) ? (float)maskA[tid] : 0.0f;
    __syncthreads();
    for (int s2 = 128; s2 > 0; s2 >>= 1) {
      if (tid < s2) red[tid] += red[tid + s2];
      __syncthreads();
    }
    if (tid == 0) { cnts[cls * 2 + 0] = red[0]; cnts[cls * 2 + 1] = (float)nP; }

    if (tid < nP) {
      float mx = -1e30f;
      for (int q = 0; q < nQ; q++) mx = fmaxf(mx, SMRAW[tid][q]);
      float s = 0.0f;
      for (int q = 0; q < nQ; q++) s += __expf(SMRAW[tid][q] - mx);
      for (int q = 0; q < nQ; q++) SP[tid][q] = __expf(SMRAW[tid][q] - mx) / s;
    }
    if (tid >= 64 && tid < 64 + nQ) {
      int q = tid - 64;
      float mx = -1e30f;
      for (int p = 0; p < nP; p++) mx = fmaxf(mx, SMRAW[p][q]);
      float s = 0.0f;
      for (int p = 0; p < nP; p++) s += __expf(SMRAW[p][q] - mx);
      for (int p = 0; p < nP; p++) SQ[q][p] = __expf(SMRAW[p][q] - mx) / s;
    }
    __syncthreads();
    float lv = 0.0f;
    if (tid < nP * nP) {
      int i = tid / nP, j = tid - i * nP;
      float t = 0.0f;
      for (int l = 0; l < nQ; l++) t += SP[i][l] * SQ[l][j];
      lv = fmaxf(0.5f - sqrtf(fmaxf(t, EPSF)), 0.0f);
    }
    red[tid] = lv;
    __syncthreads();
    for (int s2 = 128; s2 > 0; s2 >>= 1) {
      if (tid < s2) red[tid] += red[tid + s2];
      __syncthreads();
    }
    if (tid == 0) lan[cls] = red[0];
  }
}

__global__ void final_reduce(const float* __restrict__ lsp,
                             const float* __restrict__ lan,
                             const float* __restrict__ cnts,
                             const float* __restrict__ flags,
                             float* __restrict__ out, int n) {
  __shared__ float rl[256], rf[256];
  const int tid = threadIdx.x;
  float lv = 0.0f;
  if (tid < 64) {
    float nA = cnts[tid * 2 + 0];
    float nP = cnts[tid * 2 + 1];
    if (nP > 0.5f && nA > 0.5f) {
      float s = 0.0f;
      for (int p = 0; p < 8; p++) s += lsp[tid * 8 + p];
      float lc = s / (nA * nA) + lan[tid] / (nP * nP);
      lv = nP * lc;
    }
  }
  rl[tid] = lv;
  rf[tid] = flags[tid];
  __syncthreads();
  for (int s2 = 128; s2 > 0; s2 >>= 1) {
    if (tid < s2) { rl[tid] += rl[tid + s2]; rf[tid] += rf[tid + s2]; }
    __syncthreads();
  }
  if (tid == 0) {
    out[0] = rl[0] / (float)n;
    out[1] = rf[0];
  }
}

extern "C" void kernel_launch(void* const* d_in, const int* in_sizes, int n_in,
                              void* d_out, int out_size, void* d_ws,
                              size_t ws_size, hipStream_t stream) {
  const float* feature = (const float*)d_in[0];
  const int* targets = (const int*)d_in[1];
  const int n = in_sizes[1];            // 256
  const int d = in_sizes[0] / n;        // 2048
  const int nn = n * n;
  const size_t small = 512 + 64 + 128 + 256 + (size_t)n * 32;

  int S = 1;
  if (ws_size >= (small + nn + (size_t)16 * nn) * sizeof(float)) S = 16;
  else if (ws_size >= (small + nn + (size_t)4 * nn) * sizeof(float)) S = 4;

  float* ws = (float*)d_ws;
  float* lsp = ws;                 // 512
  float* lan = lsp + 512;          // 64
  float* cnts = lan + 64;          // 128
  float* flags = cnts + 128;       // 256
  float* LSEtab = flags + 256;     // n*32
  float* G = LSEtab + (size_t)n * 32;   // nn
  float* Gp = (S > 1) ? (G + nn) : G;
  float* out = (float*)d_out;

  dim3 gg(n / 64, n / 64, S);
  gemm_tile<<<gg, 256, 0, stream>>>(feature, Gp, n, d, d / S);
  if (S > 1)
    reduce_slices<<<(nn + 1023) / 1024, 256, 0, stream>>>(Gp, G, nn, S);

  stats_kernel<<<n / 4, 256, 0, stream>>>(G, targets, LSEtab, flags, n);

  dim3 gc(64, 8);
  TransitionLoss_30666066494151_kernel<<<gc, 256, 0, stream>>>(
      G, targets, LSEtab, lsp, lan, cnts, n);

  final_reduce<<<1, 256, 0, stream>>>(lsp, lan, cnts, flags, out, n);
}